// Round 2
// baseline (61.152 us; speedup 1.0000x reference)
//
#include <hip/hip_runtime.h>

// HeightVoxelLoss: B=2, X=200, Y=200, Z=16, C=17, CHOOSE=4000, HEIGHT=16 (h=1)
// loss = mean_b [ sum_valid SmoothL1(w[b,z] * log(softmax(preds)[label] + 1e-3)) / n_valid[b] ]
// w[b,z] = counts>0 ? 3 * (1/3)^(counts/max_count) : 0
//
// 2-dispatch structure (launch-overhead-bound problem, ~9.5 MB total traffic):
//   A) count_kernel: 2 blocks, reg-private counters + LDS int atomics
//      (deterministic), writes counts+weights, zeroes the done-flag.
//   B) loss_kernel: 500 blocks; per-block fixed-order tree reduction ->
//      partial; last-block-done pattern finalizes in fixed order (bit-stable).

namespace {
constexpr int B_ = 2, DX = 200, DY = 200, DZ = 16, DC = 17;
constexpr int CHOOSE_ = 4000, HEIGHT_ = 16;
constexpr int EMPTY_ = 16;
constexpr int LOSS_BLK = 256;
constexpr int NBLK = (CHOOSE_ * DZ) / LOSS_BLK;  // 250 blocks per batch
constexpr float MAXW = 3.0f, RATIO = 1.0f / 3.0f;

struct Ws {
  int counts[B_ * HEIGHT_];
  float weights[B_ * HEIGHT_];
  float partial[B_ * NBLK];
  unsigned flag;
};
}

__global__ void count_kernel(const int* __restrict__ labels,
                             const int* __restrict__ sel,
                             Ws* __restrict__ ws) {
  __shared__ int s_cnt[HEIGHT_];
  const int b = blockIdx.x;
  const int tid = threadIdx.x;
  if (tid < HEIGHT_) s_cnt[tid] = 0;
  if (tid == 0 && b == 0) ws->flag = 0u;  // arm the done-flag for loss_kernel
  __syncthreads();

  int cnt[DZ] = {};
  for (int t = tid; t < CHOOSE_; t += blockDim.x) {
    const int2 xy = ((const int2*)sel)[b * CHOOSE_ + t];
    const int4* lp = (const int4*)(labels + ((b * DX + xy.x) * DY + xy.y) * DZ);
#pragma unroll
    for (int q = 0; q < 4; ++q) {
      const int4 v = lp[q];
      cnt[q * 4 + 0] += (v.x != EMPTY_);
      cnt[q * 4 + 1] += (v.y != EMPTY_);
      cnt[q * 4 + 2] += (v.z != EMPTY_);
      cnt[q * 4 + 3] += (v.w != EMPTY_);
    }
  }
#pragma unroll
  for (int z = 0; z < DZ; ++z) atomicAdd(&s_cnt[z], cnt[z]);  // int: exact
  __syncthreads();

  if (tid < HEIGHT_) {
    float mc = 1.0f;
#pragma unroll
    for (int i = 0; i < HEIGHT_; ++i) mc = fmaxf(mc, (float)s_cnt[i]);
    const float c = (float)s_cnt[tid];
    ws->counts[b * HEIGHT_ + tid] = s_cnt[tid];
    ws->weights[b * HEIGHT_ + tid] =
        (c > 0.0f) ? MAXW * powf(RATIO, c / mc) : 0.0f;
  }
}

__global__ void loss_kernel(const float* __restrict__ preds,
                            const int* __restrict__ labels,
                            const int* __restrict__ sel,
                            Ws* __restrict__ ws,
                            float* __restrict__ out) {
  __shared__ float s_w[HEIGHT_];
  __shared__ float s_red[LOSS_BLK];
  __shared__ unsigned s_done;
  const int b = blockIdx.x;
  const int tid = threadIdx.x;

  if (tid < HEIGHT_) s_w[tid] = ws->weights[b * HEIGHT_ + tid];
  __syncthreads();

  const int vid = blockIdx.y * LOSS_BLK + tid;  // exactly CHOOSE_*DZ per batch
  const int s = vid >> 4;                       // DZ == 16
  const int z = vid & 15;
  const int2 xy = ((const int2*)sel)[b * CHOOSE_ + s];
  const int col = ((b * DX + xy.x) * DY + xy.y) * DZ + z;
  const int l = labels[col];

  float val = 0.0f;
  if (l != EMPTY_) {
    const float* p = preds + (size_t)col * DC;
    float mx = p[0];
#pragma unroll
    for (int i = 1; i < DC; ++i) mx = fmaxf(mx, p[i]);
    float se = 0.0f, pl = 0.0f;
#pragma unroll
    for (int i = 0; i < DC; ++i) {
      const float e = expf(p[i] - mx);
      se += e;
      if (i == l) pl = e;
    }
    const float wl = s_w[z] * logf(pl / se + 0.001f);
    const float a = fabsf(wl);
    val = (a < 1.0f) ? 0.5f * wl * wl : a - 0.5f;
  }

  // Deterministic fixed-pattern tree reduction within the block.
  s_red[tid] = val;
  __syncthreads();
#pragma unroll
  for (int off = LOSS_BLK / 2; off > 0; off >>= 1) {
    if (tid < off) s_red[tid] += s_red[tid + off];
    __syncthreads();
  }
  if (tid == 0) {
    __hip_atomic_store(&ws->partial[b * NBLK + blockIdx.y], s_red[0],
                       __ATOMIC_RELEASE, __HIP_MEMORY_SCOPE_AGENT);
    s_done = __hip_atomic_fetch_add(&ws->flag, 1u, __ATOMIC_ACQ_REL,
                                    __HIP_MEMORY_SCOPE_AGENT);
  }
  __syncthreads();

  if (s_done != (unsigned)(B_ * NBLK - 1)) return;

  // Last-arriving block: finalize in a FIXED order (bit-deterministic
  // regardless of which block runs this).
  float acc[B_];
#pragma unroll
  for (int bb = 0; bb < B_; ++bb) {
    acc[bb] = (tid < NBLK)
                  ? __hip_atomic_load(&ws->partial[bb * NBLK + tid],
                                      __ATOMIC_RELAXED, __HIP_MEMORY_SCOPE_AGENT)
                  : 0.0f;
  }
#pragma unroll
  for (int bb = 0; bb < B_; ++bb) {
    __syncthreads();
    s_red[tid] = acc[bb];
    __syncthreads();
#pragma unroll
    for (int off = LOSS_BLK / 2; off > 0; off >>= 1) {
      if (tid < off) s_red[tid] += s_red[tid + off];
      __syncthreads();
    }
    if (tid == 0) acc[0] = (bb == 0) ? s_red[0] : acc[0];
    if (tid == 0 && bb == B_ - 1) {
      float total = 0.0f;
      float sums[B_] = {acc[0], s_red[0]};
#pragma unroll
      for (int q = 0; q < B_; ++q) {
        int nv = 0;
#pragma unroll
        for (int i = 0; i < HEIGHT_; ++i) nv += ws->counts[q * HEIGHT_ + i];
        total += sums[q] / fmaxf((float)nv, 1.0f);
      }
      out[0] = total * (1.0f / (float)B_);
    }
  }
}

extern "C" void kernel_launch(void* const* d_in, const int* in_sizes, int n_in,
                              void* d_out, int out_size, void* d_ws, size_t ws_size,
                              hipStream_t stream) {
  const float* preds = (const float*)d_in[0];
  const int* labels = (const int*)d_in[1];
  const int* sel = (const int*)d_in[2];
  Ws* ws = (Ws*)d_ws;
  float* out = (float*)d_out;

  count_kernel<<<dim3(B_), 256, 0, stream>>>(labels, sel, ws);
  loss_kernel<<<dim3(B_, NBLK), LOSS_BLK, 0, stream>>>(preds, labels, sel, ws, out);
}

// Round 3
// 28.946 us; speedup vs baseline: 2.1126x; 2.1126x over previous
//
#include <hip/hip_runtime.h>

// HeightVoxelLoss: B=2, X=200, Y=200, Z=16, C=17, CHOOSE=4000, HEIGHT=16 (h=1)
// loss = mean_b [ sum_valid SmoothL1(w[b,z] * log(softmax(preds)[label] + 1e-3)) / n_valid[b] ]
// w[b,z] = counts>0 ? 3 * (1/3)^(counts/max_count) : 0
//
// 2-dispatch structure:
//   A) count_kernel: (B,16)x256, one column/thread, ballot+popc per z ->
//      NON-atomic partial counts pcnt[b][blk][z] (overwritten every run).
//      Also arms the done-flag.
//   B) loss_kernel: (B,250)x256; per-block: sum pcnt (L2-hit, 1KB) -> weights;
//      softmax+CE+SmoothL1; fixed-order tree reduce -> partial;
//      last-block-done finalize in fixed order (bit-deterministic).

namespace {
constexpr int B_ = 2, DX = 200, DY = 200, DZ = 16, DC = 17;
constexpr int CHOOSE_ = 4000, HEIGHT_ = 16;
constexpr int EMPTY_ = 16;
constexpr int CB = 16;  // count blocks per batch (16*256 = 4096 >= 4000)
constexpr int LOSS_BLK = 256;
constexpr int NBLK = (CHOOSE_ * DZ) / LOSS_BLK;  // 250 blocks per batch
constexpr float MAXW = 3.0f, RATIO = 1.0f / 3.0f;

struct Ws {
  int pcnt[B_][CB][HEIGHT_];
  float partial[B_ * NBLK];
  unsigned flag;
};
}

__global__ void count_kernel(const int* __restrict__ labels,
                             const int* __restrict__ sel,
                             Ws* __restrict__ ws) {
  __shared__ int s_wcnt[4][HEIGHT_];  // per-wave counts
  const int b = blockIdx.x;
  const int tid = threadIdx.x;
  const int lane = tid & 63, wv = tid >> 6;
  const int t = blockIdx.y * 256 + tid;

  if (b == 0 && blockIdx.y == 0 && tid == 0) ws->flag = 0u;  // arm done-flag

  unsigned vm = 0;  // bit z set iff label valid
  if (t < CHOOSE_) {
    const int2 xy = ((const int2*)sel)[b * CHOOSE_ + t];
    const int4* lp = (const int4*)(labels + ((b * DX + xy.x) * DY + xy.y) * DZ);
#pragma unroll
    for (int q = 0; q < 4; ++q) {
      const int4 v = lp[q];
      vm |= (unsigned)(v.x != EMPTY_) << (q * 4 + 0);
      vm |= (unsigned)(v.y != EMPTY_) << (q * 4 + 1);
      vm |= (unsigned)(v.z != EMPTY_) << (q * 4 + 2);
      vm |= (unsigned)(v.w != EMPTY_) << (q * 4 + 3);
    }
  }
#pragma unroll
  for (int z = 0; z < HEIGHT_; ++z) {
    const unsigned long long bal = __ballot((vm >> z) & 1u);
    if (lane == 0) s_wcnt[wv][z] = __popcll(bal);
  }
  __syncthreads();
  if (tid < HEIGHT_)
    ws->pcnt[b][blockIdx.y][tid] =
        s_wcnt[0][tid] + s_wcnt[1][tid] + s_wcnt[2][tid] + s_wcnt[3][tid];
}

__global__ void loss_kernel(const float* __restrict__ preds,
                            const int* __restrict__ labels,
                            const int* __restrict__ sel,
                            Ws* __restrict__ ws,
                            float* __restrict__ out) {
  __shared__ float s_w[HEIGHT_];
  __shared__ int s_cnt[HEIGHT_];
  __shared__ float s_red[LOSS_BLK];
  __shared__ float s_bsum[B_];
  __shared__ int s_nv[B_];
  __shared__ unsigned s_done;
  const int b = blockIdx.x;
  const int tid = threadIdx.x;

  // Per-block: counts from partials (L2-hit), then weights.
  if (tid < HEIGHT_) {
    int c = 0;
#pragma unroll
    for (int k = 0; k < CB; ++k) c += ws->pcnt[b][k][tid];
    s_cnt[tid] = c;
  }
  __syncthreads();
  if (tid < HEIGHT_) {
    float mc = 1.0f;
#pragma unroll
    for (int i = 0; i < HEIGHT_; ++i) mc = fmaxf(mc, (float)s_cnt[i]);
    const float c = (float)s_cnt[tid];
    s_w[tid] = (c > 0.0f) ? MAXW * powf(RATIO, c / mc) : 0.0f;
  }
  __syncthreads();

  const int vid = blockIdx.y * LOSS_BLK + tid;  // exactly CHOOSE_*DZ per batch
  const int s = vid >> 4;                       // DZ == 16
  const int z = vid & 15;
  const int2 xy = ((const int2*)sel)[b * CHOOSE_ + s];
  const int col = ((b * DX + xy.x) * DY + xy.y) * DZ + z;
  const int l = labels[col];

  float val = 0.0f;
  if (l != EMPTY_) {
    const float* p = preds + (size_t)col * DC;
    float mx = p[0];
#pragma unroll
    for (int i = 1; i < DC; ++i) mx = fmaxf(mx, p[i]);
    float se = 0.0f, pl = 0.0f;
#pragma unroll
    for (int i = 0; i < DC; ++i) {
      const float e = expf(p[i] - mx);
      se += e;
      if (i == l) pl = e;
    }
    const float wl = s_w[z] * logf(pl / se + 0.001f);
    const float a = fabsf(wl);
    val = (a < 1.0f) ? 0.5f * wl * wl : a - 0.5f;
  }

  // Deterministic fixed-pattern tree reduction within the block.
  s_red[tid] = val;
  __syncthreads();
#pragma unroll
  for (int off = LOSS_BLK / 2; off > 0; off >>= 1) {
    if (tid < off) s_red[tid] += s_red[tid + off];
    __syncthreads();
  }
  if (tid == 0) {
    __hip_atomic_store(&ws->partial[b * NBLK + blockIdx.y], s_red[0],
                       __ATOMIC_RELEASE, __HIP_MEMORY_SCOPE_AGENT);
    s_done = __hip_atomic_fetch_add(&ws->flag, 1u, __ATOMIC_ACQ_REL,
                                    __HIP_MEMORY_SCOPE_AGENT);
  }
  __syncthreads();

  if (s_done != (unsigned)(B_ * NBLK - 1)) return;

  // Last-arriving block: finalize in FIXED order (bit-deterministic).
#pragma unroll
  for (int bb = 0; bb < B_; ++bb) {
    const float v = (tid < NBLK)
                        ? __hip_atomic_load(&ws->partial[bb * NBLK + tid],
                                            __ATOMIC_RELAXED,
                                            __HIP_MEMORY_SCOPE_AGENT)
                        : 0.0f;
    __syncthreads();
    s_red[tid] = v;
    __syncthreads();
#pragma unroll
    for (int off = LOSS_BLK / 2; off > 0; off >>= 1) {
      if (tid < off) s_red[tid] += s_red[tid + off];
      __syncthreads();
    }
    if (tid == 0) s_bsum[bb] = s_red[0];
  }
  if (tid < B_) {
    int nv = 0;
#pragma unroll
    for (int k = 0; k < CB; ++k)
#pragma unroll
      for (int zz = 0; zz < HEIGHT_; ++zz) nv += ws->pcnt[tid][k][zz];
    s_nv[tid] = nv;
  }
  __syncthreads();
  if (tid == 0) {
    float total = 0.0f;
#pragma unroll
    for (int bb = 0; bb < B_; ++bb)
      total += s_bsum[bb] / fmaxf((float)s_nv[bb], 1.0f);
    out[0] = total * (1.0f / (float)B_);
  }
}

extern "C" void kernel_launch(void* const* d_in, const int* in_sizes, int n_in,
                              void* d_out, int out_size, void* d_ws, size_t ws_size,
                              hipStream_t stream) {
  const float* preds = (const float*)d_in[0];
  const int* labels = (const int*)d_in[1];
  const int* sel = (const int*)d_in[2];
  Ws* ws = (Ws*)d_ws;
  float* out = (float*)d_out;

  count_kernel<<<dim3(B_, CB), 256, 0, stream>>>(labels, sel, ws);
  loss_kernel<<<dim3(B_, NBLK), LOSS_BLK, 0, stream>>>(preds, labels, sel, ws, out);
}

// Round 4
// 20.179 us; speedup vs baseline: 3.0305x; 1.4344x over previous
//
#include <hip/hip_runtime.h>

// HeightVoxelLoss: B=2, X=200, Y=200, Z=16, C=17, CHOOSE=4000, HEIGHT=16 (h=1)
// loss = mean_b [ sum_valid SmoothL1(w[b,z] * log(softmax(preds)[label] + 1e-3)) / n_valid[b] ]
// w[b,z] = counts>0 ? 3 * (1/3)^(counts/max_count) : 0
//
// 3-dispatch structure, NO fences/spins (agent acq_rel fences cost ~10+ us on
// 8-XCD gfx950 -- R3 lesson):
//   A) count_kernel (B,16)x256: ballot counts -> pcnt (non-atomic), zero fsum.
//   B) loss_kernel  (B,250)x256: weights from pcnt on wave0 overlapped with
//      softmax; block tree-reduce; ONE relaxed u64 fixed-point atomicAdd.
//      Integer atomics are order-independent -> bit-deterministic.
//   C) final_kernel 1x64: scalar finalize.

namespace {
constexpr int B_ = 2, DX = 200, DY = 200, DZ = 16, DC = 17;
constexpr int CHOOSE_ = 4000, HEIGHT_ = 16;
constexpr int EMPTY_ = 16;
constexpr int CB = 16;                            // count blocks per batch
constexpr int LOSS_BLK = 256;
constexpr int NBLK = (CHOOSE_ * DZ) / LOSS_BLK;   // 250 per batch
constexpr float MAXW = 3.0f;
constexpr float LOG2_RATIO = -1.5849625007211562f;  // log2(1/3)
constexpr double SCALE = 16777216.0;                // 2^24 fixed point

struct Ws {
  int pcnt[B_][CB][HEIGHT_];
  unsigned long long fsum[B_];
};
}

__global__ void count_kernel(const int* __restrict__ labels,
                             const int* __restrict__ sel,
                             Ws* __restrict__ ws) {
  __shared__ int s_wcnt[4][HEIGHT_];
  const int b = blockIdx.x;
  const int tid = threadIdx.x;
  const int lane = tid & 63, wv = tid >> 6;
  const int t = blockIdx.y * 256 + tid;

  if (blockIdx.y == 0 && tid == 0) ws->fsum[b] = 0ull;  // re-zero every run

  unsigned vm = 0;  // bit z set iff label valid
  if (t < CHOOSE_) {
    const int2 xy = ((const int2*)sel)[b * CHOOSE_ + t];
    const int4* lp = (const int4*)(labels + ((b * DX + xy.x) * DY + xy.y) * DZ);
#pragma unroll
    for (int q = 0; q < 4; ++q) {
      const int4 v = lp[q];
      vm |= (unsigned)(v.x != EMPTY_) << (q * 4 + 0);
      vm |= (unsigned)(v.y != EMPTY_) << (q * 4 + 1);
      vm |= (unsigned)(v.z != EMPTY_) << (q * 4 + 2);
      vm |= (unsigned)(v.w != EMPTY_) << (q * 4 + 3);
    }
  }
#pragma unroll
  for (int z = 0; z < HEIGHT_; ++z) {
    const unsigned long long bal = __ballot((vm >> z) & 1u);
    if (lane == 0) s_wcnt[wv][z] = __popcll(bal);
  }
  __syncthreads();
  if (tid < HEIGHT_)
    ws->pcnt[b][blockIdx.y][tid] =
        s_wcnt[0][tid] + s_wcnt[1][tid] + s_wcnt[2][tid] + s_wcnt[3][tid];
}

__global__ void loss_kernel(const float* __restrict__ preds,
                            const int* __restrict__ labels,
                            const int* __restrict__ sel,
                            Ws* __restrict__ ws) {
  __shared__ float s_w[HEIGHT_];
  __shared__ int s_cnt[HEIGHT_];
  __shared__ float s_red[LOSS_BLK];
  const int b = blockIdx.x;
  const int tid = threadIdx.x;

  // Issue own-voxel loads up front; weight pipeline overlaps on wave 0.
  const int vid = blockIdx.y * LOSS_BLK + tid;  // CHOOSE_*DZ per batch exactly
  const int s = vid >> 4;                       // DZ == 16
  const int z = vid & 15;
  const int2 xy = ((const int2*)sel)[b * CHOOSE_ + s];
  const int col = ((b * DX + xy.x) * DY + xy.y) * DZ + z;
  const int l = labels[col];

  if (tid < HEIGHT_) {
    int c = 0;
#pragma unroll
    for (int k = 0; k < CB; ++k) c += ws->pcnt[b][k][tid];
    s_cnt[tid] = c;
  }
  __syncthreads();

  // Wave 0: weights. All waves: softmax + log (independent of weights).
  if (tid < HEIGHT_) {
    float mc = 1.0f;
#pragma unroll
    for (int i = 0; i < HEIGHT_; ++i) mc = fmaxf(mc, (float)s_cnt[i]);
    const float c = (float)s_cnt[tid];
    s_w[tid] = (c > 0.0f) ? MAXW * exp2f(LOG2_RATIO * (c / mc)) : 0.0f;
  }

  const bool valid = (l != EMPTY_);
  float lg = 0.0f;
  if (valid) {
    const float* p = preds + (size_t)col * DC;
    float mx = p[0];
#pragma unroll
    for (int i = 1; i < DC; ++i) mx = fmaxf(mx, p[i]);
    float se = 0.0f, pl = 0.0f;
#pragma unroll
    for (int i = 0; i < DC; ++i) {
      const float e = expf(p[i] - mx);
      se += e;
      if (i == l) pl = e;
    }
    lg = logf(pl / se + 0.001f);
  }
  __syncthreads();  // s_w ready

  float val = 0.0f;
  if (valid) {
    const float wl = s_w[z] * lg;
    const float a = fabsf(wl);
    val = (a < 1.0f) ? 0.5f * wl * wl : a - 0.5f;
  }

  // Deterministic fixed-pattern tree reduction within the block.
  s_red[tid] = val;
  __syncthreads();
#pragma unroll
  for (int off = LOSS_BLK / 2; off > 0; off >>= 1) {
    if (tid < off) s_red[tid] += s_red[tid + off];
    __syncthreads();
  }
  if (tid == 0) {
    // Fixed-point: SmoothL1 >= 0, block sum <= ~5200 -> fits easily.
    const unsigned long long q =
        (unsigned long long)llrint((double)s_red[0] * SCALE);
    atomicAdd(&ws->fsum[b], q);  // relaxed int atomic: exact + order-free
  }
}

__global__ void final_kernel(const Ws* __restrict__ ws,
                             float* __restrict__ out) {
  __shared__ int s_nv[B_];
  const int tid = threadIdx.x;  // 64 threads
  if (tid < B_) s_nv[tid] = 0;
  __syncthreads();
  {
    const int b = tid >> 5;
    const int base = (tid & 31) * 8;
    const int* pc = &ws->pcnt[b][0][0];  // 256 ints per batch
    int s = 0;
#pragma unroll
    for (int i = 0; i < 8; ++i) s += pc[base + i];
    atomicAdd(&s_nv[b], s);  // LDS int atomic: exact
  }
  __syncthreads();
  if (tid == 0) {
    double total = 0.0;
#pragma unroll
    for (int b = 0; b < B_; ++b) {
      const double sum = (double)ws->fsum[b] / SCALE;
      const int nv = s_nv[b] < 1 ? 1 : s_nv[b];
      total += sum / (double)nv;
    }
    out[0] = (float)(total / (double)B_);
  }
}

extern "C" void kernel_launch(void* const* d_in, const int* in_sizes, int n_in,
                              void* d_out, int out_size, void* d_ws, size_t ws_size,
                              hipStream_t stream) {
  const float* preds = (const float*)d_in[0];
  const int* labels = (const int*)d_in[1];
  const int* sel = (const int*)d_in[2];
  Ws* ws = (Ws*)d_ws;
  float* out = (float*)d_out;

  count_kernel<<<dim3(B_, CB), 256, 0, stream>>>(labels, sel, ws);
  loss_kernel<<<dim3(B_, NBLK), 256, 0, stream>>>(preds, labels, sel, ws);
  final_kernel<<<1, 64, 0, stream>>>(ws, out);
}